// Round 4
// baseline (250.794 us; speedup 1.0000x reference)
//
#include <hip/hip_runtime.h>
#include <math.h>

// Problem constants
#define NN 8
#define C_TOTAL 448
#define CC 100
#define HH 56
#define WW 56
#define HW (HH*WW)          // 3136
#define NPIX4 (HW/4)        // 784 float4 / half4 columns
#define OH 224
#define OW 224
#define NT4 13              // ceil(784 / 64) pixel-quad tiles per wave

typedef __attribute__((ext_vector_type(4))) _Float16 half4;

__device__ __forceinline__ void fma4(float4& acc, const float4 a, const float4 b) {
    acc.x = fmaf(a.x, b.x, acc.x);
    acc.y = fmaf(a.y, b.y, acc.y);
    acc.z = fmaf(a.z, b.z, acc.z);
    acc.w = fmaf(a.w, b.w, acc.w);
}
__device__ __forceinline__ float4 h2f(const half4 h) {
    float4 r; r.x = (float)h.x; r.y = (float)h.y; r.z = (float)h.z; r.w = (float)h.w;
    return r;
}

// ---------------------------------------------------------------------------
// Kernel 0: x[n,c,pix] = fmaps[n, sel[c], pix] - mean[c, pix]  -> fp16 (half4)
// ---------------------------------------------------------------------------
__global__ __launch_bounds__(256) void prep_x_kernel(
    const float* __restrict__ fmaps, const int* __restrict__ sel,
    const float* __restrict__ mean, half4* __restrict__ xbuf)
{
    const int idx = blockIdx.x * 256 + threadIdx.x;
    const int total = NN * CC * NPIX4;
    if (idx >= total) return;
    const int p4 = idx % NPIX4;
    const int c  = (idx / NPIX4) % CC;
    const int n  = idx / (NPIX4 * CC);

    const float4* f4 = (const float4*)fmaps;
    const float4* m4 = (const float4*)mean;

    const float4 f = f4[((size_t)n * C_TOTAL + sel[c]) * NPIX4 + p4];
    const float4 m = m4[(size_t)c * NPIX4 + p4];
    half4 r;
    r.x = (_Float16)(f.x - m.x);
    r.y = (_Float16)(f.y - m.y);
    r.z = (_Float16)(f.z - m.z);
    r.w = (_Float16)(f.w - m.w);
    xbuf[((size_t)n * CC + c) * NPIX4 + p4] = r;
}

// ---------------------------------------------------------------------------
// Kernel 1: zero the smap2 accumulator (ws is poisoned 0xAA before each call)
// ---------------------------------------------------------------------------
__global__ __launch_bounds__(256) void zero_kernel(float4* __restrict__ smap2)
{
    const int idx = blockIdx.x * 256 + threadIdx.x;
    if (idx < NN * NPIX4) smap2[idx] = make_float4(0.f, 0.f, 0.f, 0.f);
}

// ---------------------------------------------------------------------------
// Kernel 2: per-ROW symmetric quadratic-form slice, atomically accumulated.
//   block (tile, r):  q_r[n,pix] = 2*x_r*(0.5*x_r*cov[r,r] + sum_{d>r} x_d*cov[r,d])
//   sum over r of q_r == x^T cov x   (cov bitwise symmetric).
// Block = 512 threads = 8 waves (wave = image n); lane owns a pixel quad.
// Rows launch longest-first (r ascending => cost 100-r descending).
// ---------------------------------------------------------------------------
__global__ __launch_bounds__(512) void qform_kernel(
    const half4* __restrict__ xbuf, const float* __restrict__ cov,
    float* __restrict__ smap2)
{
    const int tile = blockIdx.x % NT4;
    const int r    = blockIdx.x / NT4;      // 0..99
    const int n    = threadIdx.x >> 6;
    const int p4   = tile * 64 + (threadIdx.x & 63);
    if (p4 >= NPIX4) return;

    const half4*  x4 = xbuf + (size_t)n * CC * NPIX4;
    const float4* c4 = (const float4*)cov;

    const float4* covp = c4 + ((size_t)r * CC + r) * NPIX4 + p4;   // cov[r, d=r..]
    const half4*  xp   = x4 + (size_t)r * NPIX4 + p4;              // x[d=r..]

    // d == r : half-weight diagonal
    const float4 xr = h2f(*xp);
    float4 acc;
    {
        const float4 cd = *covp;
        acc.x = 0.5f * xr.x * cd.x;
        acc.y = 0.5f * xr.y * cd.y;
        acc.z = 0.5f * xr.z * cd.z;
        acc.w = 0.5f * xr.w * cd.w;
    }
    xp += NPIX4; covp += NPIX4;

    // d = r+1 .. 99, unroll 4 with grouped loads
    int d = r + 1;
    for (; d + 3 < CC; d += 4) {
        const half4  h0 = xp[0], h1 = xp[NPIX4], h2 = xp[2*NPIX4], h3 = xp[3*NPIX4];
        const float4 g0 = covp[0], g1 = covp[NPIX4], g2 = covp[2*NPIX4], g3 = covp[3*NPIX4];
        fma4(acc, h2f(h0), g0);
        fma4(acc, h2f(h1), g1);
        fma4(acc, h2f(h2), g2);
        fma4(acc, h2f(h3), g3);
        xp += 4*NPIX4; covp += 4*NPIX4;
    }
    for (; d < CC; ++d) {
        fma4(acc, h2f(*xp), *covp);
        xp += NPIX4; covp += NPIX4;
    }

    float* sp = smap2 + (size_t)n * HW + 4 * p4;
    unsafeAtomicAdd(sp + 0, 2.0f * xr.x * acc.x);
    unsafeAtomicAdd(sp + 1, 2.0f * xr.y * acc.y);
    unsafeAtomicAdd(sp + 2, 2.0f * xr.z * acc.z);
    unsafeAtomicAdd(sp + 3, 2.0f * xr.w * acc.w);
}

// ---------------------------------------------------------------------------
// Kernel 3: bilinear x4 upsample (half-pixel, edge clamp) of sqrt(smap2),
//           then normalize.  sqrt applied at the 4 corners == ref order.
// ---------------------------------------------------------------------------
__global__ __launch_bounds__(256) void upsample_kernel(
    const float* __restrict__ smap2,
    const float* __restrict__ minp, const float* __restrict__ maxp,
    float* __restrict__ out)
{
    const int idx = blockIdx.x * 256 + threadIdx.x;
    const int total = NN * OH * OW;
    if (idx >= total) return;

    const int ox = idx % OW;
    const int oy = (idx / OW) % OH;
    const int n  = idx / (OW * OH);

    const float fy = oy * 0.25f - 0.375f;
    const float fx = ox * 0.25f - 0.375f;

    int y0 = (int)floorf(fy);
    int x0 = (int)floorf(fx);
    const float wy = fy - (float)y0;
    const float wx = fx - (float)x0;
    int y1 = min(y0 + 1, HH - 1); y0 = max(y0, 0);
    int x1 = min(x0 + 1, WW - 1); x0 = max(x0, 0);

    const float* s = smap2 + (size_t)n * HW;
    const float v00 = sqrtf(fmaxf(s[y0 * WW + x0], 0.f));
    const float v01 = sqrtf(fmaxf(s[y0 * WW + x1], 0.f));
    const float v10 = sqrtf(fmaxf(s[y1 * WW + x0], 0.f));
    const float v11 = sqrtf(fmaxf(s[y1 * WW + x1], 0.f));

    const float v = (1.0f - wy) * ((1.0f - wx) * v00 + wx * v01)
                  +          wy * ((1.0f - wx) * v10 + wx * v11);

    const float mn = *minp;
    const float mx = *maxp;
    out[idx] = (v - mn) / (mx - mn);
}

// ---------------------------------------------------------------------------
extern "C" void kernel_launch(void* const* d_in, const int* in_sizes, int n_in,
                              void* d_out, int out_size, void* d_ws, size_t ws_size,
                              hipStream_t stream)
{
    const float* fmaps = (const float*)d_in[0];
    const int*   sel   = (const int*)  d_in[1];
    const float* mean  = (const float*)d_in[2];
    const float* cov   = (const float*)d_in[3];
    const float* minp  = (const float*)d_in[4];
    const float* maxp  = (const float*)d_in[5];
    float* out = (float*)d_out;

    half4* xbuf  = (half4*)d_ws;                                  // NN*CC*HW fp16 (5.0 MB)
    float* smap2 = (float*)((char*)d_ws + (size_t)NN*CC*HW*2);    // NN*HW f32 (0.1 MB)

    {
        const int total = NN * CC * NPIX4;
        prep_x_kernel<<<(total + 255) / 256, 256, 0, stream>>>(fmaps, sel, mean, xbuf);
    }
    {
        const int total = NN * NPIX4;   // float4 elements
        zero_kernel<<<(total + 255) / 256, 256, 0, stream>>>((float4*)smap2);
    }
    qform_kernel<<<NT4 * CC, 512, 0, stream>>>(xbuf, cov, smap2);
    {
        const int total = NN * OH * OW;
        upsample_kernel<<<(total + 255) / 256, 256, 0, stream>>>(smap2, minp, maxp, out);
    }
}

// Round 5
// 228.244 us; speedup vs baseline: 1.0988x; 1.0988x over previous
//
#include <hip/hip_runtime.h>
#include <math.h>

// Problem constants
#define NN 8
#define C_TOTAL 448
#define CC 100
#define HH 56
#define WW 56
#define HW (HH*WW)          // 3136
#define NPIX4 (HW/4)        // 784 quads (float4 pixel groups)
#define OH 224
#define OW 224
#define NPAIR 50            // row pairs (r, 99-r), uniform cost
#define NT4 13              // ceil(784/64) quad tiles

typedef __attribute__((ext_vector_type(4))) _Float16 half4;

__device__ __forceinline__ void fma4(float4& acc, const float4 a, const float4 b) {
    acc.x = fmaf(a.x, b.x, acc.x);
    acc.y = fmaf(a.y, b.y, acc.y);
    acc.z = fmaf(a.z, b.z, acc.z);
    acc.w = fmaf(a.w, b.w, acc.w);
}
__device__ __forceinline__ float4 h2f(const half4 h) {
    float4 r; r.x = (float)h.x; r.y = (float)h.y; r.z = (float)h.z; r.w = (float)h.w;
    return r;
}

// ---------------------------------------------------------------------------
// Kernel 0: x -> fp16, TRANSPOSED layout xbuf[d][quad][n] (half4 elements).
// One thread per (c, quad); loops n internally; writes one contiguous 64 B run.
// ---------------------------------------------------------------------------
__global__ __launch_bounds__(256) void prep_x_kernel(
    const float* __restrict__ fmaps, const int* __restrict__ sel,
    const float* __restrict__ mean, half4* __restrict__ xbuf)
{
    const int idx = blockIdx.x * 256 + threadIdx.x;
    if (idx >= CC * NPIX4) return;
    const int quad = idx % NPIX4;
    const int c    = idx / NPIX4;

    const float4* f4 = (const float4*)fmaps;
    const float4  m  = ((const float4*)mean)[(size_t)c * NPIX4 + quad];
    const int     sc = sel[c];

    half4 hv[NN];
#pragma unroll
    for (int n = 0; n < NN; ++n) {
        const float4 f = f4[((size_t)n * C_TOTAL + sc) * NPIX4 + quad];
        half4 h;
        h.x = (_Float16)(f.x - m.x);
        h.y = (_Float16)(f.y - m.y);
        h.z = (_Float16)(f.z - m.z);
        h.w = (_Float16)(f.w - m.w);
        hv[n] = h;
    }
    half4* dst = xbuf + ((size_t)c * NPIX4 + quad) * NN;   // 64 B contiguous
#pragma unroll
    for (int n = 0; n < NN; ++n) dst[n] = hv[n];
}

// ---------------------------------------------------------------------------
// Kernel 1: pair (r, s=99-r) symmetric quadratic form, wave-transposed:
//   wave w handles cols d = row+w, row+w+8, ... and ALL 8 images per col.
//   Each cov float4 is loaded exactly once per block (no duplicate requests).
//   partial[n] = sum over segments 2*x_row[n]*( sum_d w_d * x_d[n]*cov[row,d] )
//   Cross-wave sum via one 64 KB LDS dump + single barrier -> qpart[r][n][quad].
// ---------------------------------------------------------------------------
__global__ __launch_bounds__(512, 4) void qform_kernel(
    const half4* __restrict__ xbuf, const float* __restrict__ cov,
    float* __restrict__ qpart)
{
    __shared__ float4 lred[NN * NN * 64];   // [wave][n][lane] = 64 KB

    const int tile = blockIdx.x % NT4;
    const int r    = blockIdx.x / NT4;      // 0..49
    const int s    = CC - 1 - r;            // 99-r
    const int w    = threadIdx.x >> 6;      // wave id 0..7
    const int lane = threadIdx.x & 63;
    const int qraw = tile * 64 + lane;
    const bool valid = qraw < NPIX4;
    const int quad = valid ? qraw : (NPIX4 - 1);   // clamp, no early return

    const float4* c4 = (const float4*)cov;

    float4 part[NN];
#pragma unroll
    for (int n = 0; n < NN; ++n) part[n] = make_float4(0.f, 0.f, 0.f, 0.f);

    for (int seg = 0; seg < 2; ++seg) {
        const int row = seg ? s : r;

        float4 acc[NN];
#pragma unroll
        for (int n = 0; n < NN; ++n) acc[n] = make_float4(0.f, 0.f, 0.f, 0.f);

        // cols d = row + w, step 8 (wave-uniform trip count)
        for (int d = row + w; d < CC; d += NN) {
            float4 cv = c4[((size_t)row * CC + d) * NPIX4 + quad];
            if (d == row) { cv.x *= 0.5f; cv.y *= 0.5f; cv.z *= 0.5f; cv.w *= 0.5f; }
            const half4* xp = xbuf + ((size_t)d * NPIX4 + quad) * NN;  // 64 B: 8 images
            half4 hv[NN];
#pragma unroll
            for (int n = 0; n < NN; ++n) hv[n] = xp[n];
#pragma unroll
            for (int n = 0; n < NN; ++n) fma4(acc[n], h2f(hv[n]), cv);
        }

        // fold: part[n] += 2 * x_row[n] * acc[n]
        const half4* xrp = xbuf + ((size_t)row * NPIX4 + quad) * NN;
#pragma unroll
        for (int n = 0; n < NN; ++n) {
            const float4 xr = h2f(xrp[n]);
            part[n].x = fmaf(2.f * xr.x, acc[n].x, part[n].x);
            part[n].y = fmaf(2.f * xr.y, acc[n].y, part[n].y);
            part[n].z = fmaf(2.f * xr.z, acc[n].z, part[n].z);
            part[n].w = fmaf(2.f * xr.w, acc[n].w, part[n].w);
        }
    }

    // cross-wave reduction: dump, barrier, thread-block sums wave partials
#pragma unroll
    for (int n = 0; n < NN; ++n) lred[(w * NN + n) * 64 + lane] = part[n];
    __syncthreads();

    {
        const int n = w;   // wave w reduces image n
        float4 sum = make_float4(0.f, 0.f, 0.f, 0.f);
#pragma unroll
        for (int ww = 0; ww < NN; ++ww) {
            const float4 v = lred[(ww * NN + n) * 64 + lane];
            sum.x += v.x; sum.y += v.y; sum.z += v.z; sum.w += v.w;
        }
        if (valid) {
            ((float4*)qpart)[((size_t)r * NN + n) * NPIX4 + qraw] = sum;
        }
    }
}

// ---------------------------------------------------------------------------
// Kernel 2: reduce partials over the 50 pairs, sqrt -> s_map (N,HW)
// ---------------------------------------------------------------------------
__global__ __launch_bounds__(256) void reduce_kernel(
    const float* __restrict__ qpart, float* __restrict__ smap)
{
    const int idx = blockIdx.x * 256 + threadIdx.x;   // over N*NPIX4
    if (idx >= NN * NPIX4) return;
    const int p4 = idx % NPIX4;
    const int n  = idx / NPIX4;

    const float4* qp = (const float4*)qpart;
    float4 acc = make_float4(0.f, 0.f, 0.f, 0.f);
#pragma unroll
    for (int k = 0; k < NPAIR; ++k) {
        const float4 v = qp[((size_t)k * NN + n) * NPIX4 + p4];
        acc.x += v.x; acc.y += v.y; acc.z += v.z; acc.w += v.w;
    }
    float4 o;
    o.x = sqrtf(fmaxf(acc.x, 0.f));
    o.y = sqrtf(fmaxf(acc.y, 0.f));
    o.z = sqrtf(fmaxf(acc.z, 0.f));
    o.w = sqrtf(fmaxf(acc.w, 0.f));
    ((float4*)smap)[(size_t)n * NPIX4 + p4] = o;
}

// ---------------------------------------------------------------------------
// Kernel 3: bilinear x4 upsample (half-pixel, edge clamp) + normalize
// ---------------------------------------------------------------------------
__global__ __launch_bounds__(256) void upsample_kernel(
    const float* __restrict__ smap,
    const float* __restrict__ minp, const float* __restrict__ maxp,
    float* __restrict__ out)
{
    const int idx = blockIdx.x * 256 + threadIdx.x;
    const int total = NN * OH * OW;
    if (idx >= total) return;

    const int ox = idx % OW;
    const int oy = (idx / OW) % OH;
    const int n  = idx / (OW * OH);

    const float fy = oy * 0.25f - 0.375f;
    const float fx = ox * 0.25f - 0.375f;

    int y0 = (int)floorf(fy);
    int x0 = (int)floorf(fx);
    const float wy = fy - (float)y0;
    const float wx = fx - (float)x0;
    int y1 = min(y0 + 1, HH - 1); y0 = max(y0, 0);
    int x1 = min(x0 + 1, WW - 1); x0 = max(x0, 0);

    const float* s = smap + (size_t)n * HW;
    const float v00 = s[y0 * WW + x0];
    const float v01 = s[y0 * WW + x1];
    const float v10 = s[y1 * WW + x0];
    const float v11 = s[y1 * WW + x1];

    const float v = (1.0f - wy) * ((1.0f - wx) * v00 + wx * v01)
                  +          wy * ((1.0f - wx) * v10 + wx * v11);

    const float mn = *minp;
    const float mx = *maxp;
    out[idx] = (v - mn) / (mx - mn);
}

// ---------------------------------------------------------------------------
extern "C" void kernel_launch(void* const* d_in, const int* in_sizes, int n_in,
                              void* d_out, int out_size, void* d_ws, size_t ws_size,
                              hipStream_t stream)
{
    const float* fmaps = (const float*)d_in[0];
    const int*   sel   = (const int*)  d_in[1];
    const float* mean  = (const float*)d_in[2];
    const float* cov   = (const float*)d_in[3];
    const float* minp  = (const float*)d_in[4];
    const float* maxp  = (const float*)d_in[5];
    float* out = (float*)d_out;

    half4* xbuf  = (half4*)d_ws;                                  // CC*NPIX4*NN half4 = 5.0 MB
    float* qpart = (float*)((char*)d_ws + (size_t)CC*NPIX4*NN*8); // NPAIR*NN*HW f32 = 5.0 MB
    float* smap  = qpart + (size_t)NPAIR * NN * HW;               // NN*HW f32 = 0.1 MB

    {
        const int total = CC * NPIX4;
        prep_x_kernel<<<(total + 255) / 256, 256, 0, stream>>>(fmaps, sel, mean, xbuf);
    }
    qform_kernel<<<NT4 * NPAIR, 512, 0, stream>>>(xbuf, cov, qpart);
    {
        const int total = NN * NPIX4;
        reduce_kernel<<<(total + 255) / 256, 256, 0, stream>>>(qpart, smap);
    }
    {
        const int total = NN * OH * OW;
        upsample_kernel<<<(total + 255) / 256, 256, 0, stream>>>(smap, minp, maxp, out);
    }
}